// Round 15
// baseline (187.686 us; speedup 1.0000x reference)
//
#include <hip/hip_runtime.h>
#include <math.h>

// ---------- constants ----------
#define B_  2
#define T_  4096
#define DM  2048
#define H_  16
#define HKV 4
#define DV_ 64
#define MB_ 64
#define LW_ 1024
#define REMOTE 3072     // T - LW
#define NBLK 48         // REMOTE/MB
#define KTOT 1072       // NBLK + LW
#define NTILES 17       // ceil(1072/64)

typedef __bf16 bf16x8 __attribute__((ext_vector_type(8)));
typedef float  f32x4  __attribute__((ext_vector_type(4)));

__device__ __forceinline__ float bf2f(unsigned short u) {
    unsigned int x = ((unsigned int)u) << 16;
    return __builtin_bit_cast(float, x);
}
__device__ __forceinline__ unsigned short f2bf(float f) {
    unsigned int x = __builtin_bit_cast(unsigned int, f);
    x = x + 0x7fffu + ((x >> 16) & 1u);   // round-to-nearest-even
    return (unsigned short)(x >> 16);
}

// async global->LDS, 16B per lane; LDS dest = wave-uniform base + lane*16
__device__ __forceinline__ void gload16(const void* gsrc, unsigned short* ldst) {
    __builtin_amdgcn_global_load_lds(
        (const __attribute__((address_space(1))) void*)gsrc,
        (__attribute__((address_space(3))) void*)ldst,
        16, 0, 0);
}

// ---------- prep: ALL weight transposes + x->bf16 cvt in ONE launch -------
// blocks [0,5120): transposes; [5120,6144): cvt grid-stride (16 ushort4 each)
__global__ void prep_all(const float* __restrict__ x,
                         const float* __restrict__ Wq_sem,
                         const float* __restrict__ Wq_geo,
                         const float* __restrict__ Wk_sem,
                         const float* __restrict__ Wk_geo,
                         const float* __restrict__ Wv,
                         const float* __restrict__ Wo,
                         unsigned short* __restrict__ xb,
                         unsigned short* __restrict__ WcatT,
                         unsigned short* __restrict__ WoT) {
    const int bid = blockIdx.x;
    if (bid >= 5120) {
        // cvt: 1024 blocks x 256 thr x 16 iter = 4,194,304 ushort4
        const int base = (bid - 5120) * 256 + threadIdx.x;
        #pragma unroll
        for (int it = 0; it < 16; it++) {
            int i = base + it * 262144;
            float4 v = ((const float4*)x)[i];
            ((ushort4*)xb)[i] =
                make_ushort4(f2bf(v.x), f2bf(v.y), f2bf(v.z), f2bf(v.w));
        }
        return;
    }
    __shared__ float tile[32][33];
    const float* src; unsigned short* dst; int C, R, tiles_x, lt;
    if (bid < 1024)      { src = Wq_sem; dst = WcatT;                       R = 2048; C = 512;  tiles_x = 16; lt = bid; }
    else if (bid < 2048) { src = Wq_geo; dst = WcatT + (size_t)512  * 2048; R = 2048; C = 512;  tiles_x = 16; lt = bid - 1024; }
    else if (bid < 2304) { src = Wk_sem; dst = WcatT + (size_t)1024 * 2048; R = 2048; C = 128;  tiles_x = 4;  lt = bid - 2048; }
    else if (bid < 2560) { src = Wk_geo; dst = WcatT + (size_t)1152 * 2048; R = 2048; C = 128;  tiles_x = 4;  lt = bid - 2304; }
    else if (bid < 3072) { src = Wv;     dst = WcatT + (size_t)1280 * 2048; R = 2048; C = 256;  tiles_x = 8;  lt = bid - 2560; }
    else                 { src = Wo;     dst = WoT;                         R = 1024; C = 2048; tiles_x = 64; lt = bid - 3072; }
    const int ct = lt % tiles_x, rt = lt / tiles_x;
    const int tx = threadIdx.x & 31, ty = threadIdx.x >> 5;
    #pragma unroll
    for (int i = ty; i < 32; i += 8)
        tile[i][tx] = src[(size_t)(rt * 32 + i) * C + ct * 32 + tx];
    __syncthreads();
    #pragma unroll
    for (int i = ty; i < 32; i += 8)
        dst[(size_t)(ct * 32 + i) * R + rt * 32 + tx] = f2bf(tile[tx][i]);
}

// ---------- projection GEMM: 128x128, ring-3, counted vmcnt(4) ------------
// (R11 config — measured 80.2 us.)  A = xb (bf16), B = WcatT.  Fused
// RoPE + KV mem-block pooling epilogue.  Swizzle both-sides, conflict-free.
__global__ __launch_bounds__(256, 3) void gemmProj(
    const unsigned short* __restrict__ A,
    const unsigned short* __restrict__ BT,
    unsigned short* __restrict__ qcat,
    unsigned short* __restrict__ kp,    // [bg][key][64]
    unsigned short* __restrict__ vt,    // [bg][d][KTOT]
    int K, int nbx)
{
    extern __shared__ __align__(16) unsigned short lds[];  // 3*8192 ushorts

    const int tid = threadIdx.x;
    const int lane = tid & 63, w = tid >> 6;   // 4 waves: 2x2
    const int wr = w >> 1, wc = w & 1;
    const int l15 = lane & 15, lg = lane >> 4;

    const int cpx = gridDim.x >> 3;
    const int swz = (blockIdx.x & 7) * cpx + (blockIdx.x >> 3);
    const int bx = swz % nbx, by = swz / nbx;
    const int row0 = by * 128, col0 = bx * 128;

    const int scol = ((lane & 3) ^ ((lane >> 3) & 3)) * 8;
    const int srA = w * 16 + (lane >> 2);           // + j*64
    const unsigned short* Ag = A  + (size_t)row0 * K;
    const unsigned short* Bg = BT + (size_t)col0 * K;

    const int rdsw = (lg ^ ((l15 >> 1) & 3)) * 8;
    const int aoff = (wr * 64 + l15) * 32 + rdsw;   // + mf*512
    const int boff = (wc * 64 + l15) * 32 + rdsw;   // + nf*512

    const int NT = K >> 5;
    f32x4 acc[4][4] = {};

    auto stage = [&](int s, int kk) {
        unsigned short* sa = lds + s * 8192;
        unsigned short* sb = sa + 4096;
        #pragma unroll
        for (int j = 0; j < 2; j++) {
            gload16(Ag + (size_t)(srA + j * 64) * K + kk + scol,
                    sa + (j * 256 + w * 64) * 8);
            gload16(Bg + (size_t)(srA + j * 64) * K + kk + scol,
                    sb + (j * 256 + w * 64) * 8);
        }
    };

    stage(0, 0);
    stage(1, 32);
    asm volatile("s_waitcnt vmcnt(4)" ::: "memory");

    int rs = 0;
    for (int t = 0; t < NT; ++t) {
        __builtin_amdgcn_s_barrier();
        if (t + 2 < NT) stage(rs == 0 ? 2 : rs - 1, (t + 2) << 5);

        const unsigned short* As_ = lds + rs * 8192;
        const unsigned short* Bs_ = As_ + 4096;
        bf16x8 af[4], bfr[4];
        #pragma unroll
        for (int mf = 0; mf < 4; mf++)
            af[mf] = __builtin_bit_cast(bf16x8, *(const uint4*)&As_[aoff + mf * 512]);
        #pragma unroll
        for (int nf = 0; nf < 4; nf++)
            bfr[nf] = __builtin_bit_cast(bf16x8, *(const uint4*)&Bs_[boff + nf * 512]);

        __builtin_amdgcn_s_setprio(1);
        #pragma unroll
        for (int mf = 0; mf < 4; mf++)
            #pragma unroll
            for (int nf = 0; nf < 4; nf++)
                acc[mf][nf] = __builtin_amdgcn_mfma_f32_16x16x32_bf16(
                                  af[mf], bfr[nf], acc[mf][nf], 0, 0, 0);
        __builtin_amdgcn_s_setprio(0);

        if (t + 2 < NT) asm volatile("s_waitcnt vmcnt(4)" ::: "memory");
        else            asm volatile("s_waitcnt vmcnt(0)" ::: "memory");
        rs = (rs == 2) ? 0 : rs + 1;
    }

    // ---- fused epilogue (validated since R8) ----
    const int cspan = col0 + wc * 64;
    const int tbase = row0 & 4095;
    const int bq = row0 >> 12;

    if ((cspan >= 512 && cspan < 1024) || (cspan >= 1152 && cspan < 1280)) {
        const float invf = exp2f(-(float)l15 * 0.8304820237218406f);
        #pragma unroll
        for (int mf = 0; mf < 4; mf++) {
            #pragma unroll
            for (int r = 0; r < 4; r++) {
                float s, c;
                sincosf((float)(tbase + wr*64 + mf*16 + lg*4 + r) * invf, &s, &c);
                float a0 = acc[mf][0][r], a1 = acc[mf][1][r];
                acc[mf][0][r] = a0 * c - a1 * s;
                acc[mf][1][r] = a1 * c + a0 * s;
                float a2 = acc[mf][2][r], a3 = acc[mf][3][r];
                acc[mf][2][r] = a2 * c - a3 * s;
                acc[mf][3][r] = a3 * c + a2 * s;
            }
        }
    }

    if (cspan < 1024) {
        #pragma unroll
        for (int nf = 0; nf < 4; nf++) {
            int col = cspan + nf * 16 + l15;
            int h = (col < 512) ? (col >> 5) : ((col - 512) >> 5);
            int d = (col < 512) ? (col & 31) : (32 + (col & 31));
            unsigned short* qb =
                qcat + (((size_t)(bq * 16 + h)) * 4096 + tbase) * 64 + d;
            #pragma unroll
            for (int mf = 0; mf < 4; mf++)
                #pragma unroll
                for (int r = 0; r < 4; r++)
                    qb[(size_t)(wr*64 + mf*16 + lg*4 + r) * 64] =
                        f2bf(acc[mf][nf][r]);
        }
    } else if (tbase >= REMOTE) {
        #pragma unroll
        for (int nf = 0; nf < 4; nf++) {
            int col = cspan + nf * 16 + l15;
            #pragma unroll
            for (int mf = 0; mf < 4; mf++)
                #pragma unroll
                for (int r = 0; r < 4; r++) {
                    int key = tbase + wr*64 + mf*16 + lg*4 + r - 3024;
                    unsigned short hv = f2bf(acc[mf][nf][r]);
                    if (col < 1280) {
                        int g, dk;
                        if (col < 1152) { g = (col - 1024) >> 5; dk = col & 31; }
                        else            { g = (col - 1152) >> 5; dk = 32 + (col & 31); }
                        kp[(((size_t)(bq*4 + g)) * KTOT + key) * 64 + dk] = hv;
                    } else {
                        int g = (col - 1280) >> 6, dv = col & 63;
                        vt[(((size_t)(bq*4 + g)) * 64 + dv) * KTOT + key] = hv;
                    }
                }
        }
    } else {
        #pragma unroll
        for (int nf = 0; nf < 4; nf++) {
            float ps = 0.f;
            #pragma unroll
            for (int mf = 0; mf < 4; mf++)
                #pragma unroll
                for (int r = 0; r < 4; r++) ps += acc[mf][nf][r];
            ps += __shfl_xor(ps, 16);
            ps += __shfl_xor(ps, 32);
            if (lane < 16) {
                int col = cspan + nf * 16 + l15;
                int key = (tbase >> 6) + wr;
                unsigned short hv = f2bf(ps * (1.f / 64.f));
                if (col < 1280) {
                    int g, dk;
                    if (col < 1152) { g = (col - 1024) >> 5; dk = col & 31; }
                    else            { g = (col - 1152) >> 5; dk = 32 + (col & 31); }
                    kp[(((size_t)(bq*4 + g)) * KTOT + key) * 64 + dk] = hv;
                } else {
                    int g = (col - 1280) >> 6, dv = col & 63;
                    vt[(((size_t)(bq*4 + g)) * 64 + dv) * KTOT + key] = hv;
                }
            }
        }
    }
}

// ---------- Wo GEMM: 128x256 tile, ring-3, counted vmcnt(6) ----------------
// (R14 config — measured fastest.)  512 blocks = 2/CU single round.
__global__ __launch_bounds__(256, 2) void gemmWo(
    const unsigned short* __restrict__ A,
    const unsigned short* __restrict__ BT,
    float* __restrict__ outF,
    int N, int K, int nbx)
{
    extern __shared__ __align__(16) unsigned short lds[];  // 3*12288 ushorts

    const int tid = threadIdx.x;
    const int lane = tid & 63, w = tid >> 6;
    const int l15 = lane & 15, lg = lane >> 4;

    const int cpx = gridDim.x >> 3;
    const int swz = (blockIdx.x & 7) * cpx + (blockIdx.x >> 3);
    const int bx = swz % nbx, by = swz / nbx;
    const int row0 = by * 128, col0 = bx * 256;

    const int scol = ((lane & 3) ^ ((lane >> 3) & 3)) * 8;
    const int srA = w * 16 + (lane >> 2);           // + j*64
    const unsigned short* Ag = A  + (size_t)row0 * K;
    const unsigned short* Bg = BT + (size_t)col0 * K;

    const int rdsw = (lg ^ ((l15 >> 1) & 3)) * 8;
    const int aoff = l15 * 32 + rdsw;               // + mf*512, mf 0..7
    const int boff = (w * 64 + l15) * 32 + rdsw;    // + nf*512

    const int NT = K >> 5;
    f32x4 acc[8][4] = {};

    auto stage = [&](int s, int kk) {
        unsigned short* sa = lds + s * 12288;
        unsigned short* sb = sa + 4096;
        #pragma unroll
        for (int j = 0; j < 2; j++)                 // A: 128 rows
            gload16(Ag + (size_t)(srA + j * 64) * K + kk + scol,
                    sa + (j * 256 + w * 64) * 8);
        #pragma unroll
        for (int j = 0; j < 4; j++)                 // B: 256 rows
            gload16(Bg + (size_t)(srA + j * 64) * K + kk + scol,
                    sb + (j * 256 + w * 64) * 8);
    };

    stage(0, 0);
    stage(1, 32);
    asm volatile("s_waitcnt vmcnt(6)" ::: "memory");   // tile0 landed

    int rs = 0;
    for (int t = 0; t < NT; ++t) {
        __builtin_amdgcn_s_barrier();
        if (t + 2 < NT) stage(rs == 0 ? 2 : rs - 1, (t + 2) << 5);

        const unsigned short* As_ = lds + rs * 12288;
        const unsigned short* Bs_ = As_ + 4096;
        bf16x8 af[8], bfr[4];
        #pragma unroll
        for (int mf = 0; mf < 8; mf++)
            af[mf] = __builtin_bit_cast(bf16x8, *(const uint4*)&As_[aoff + mf * 512]);
        #pragma unroll
        for (int nf = 0; nf < 4; nf++)
            bfr[nf] = __builtin_bit_cast(bf16x8, *(const uint4*)&Bs_[boff + nf * 512]);

        __builtin_amdgcn_s_setprio(1);
        #pragma unroll
        for (int mf = 0; mf < 8; mf++)
            #pragma unroll
            for (int nf = 0; nf < 4; nf++)
                acc[mf][nf] = __builtin_amdgcn_mfma_f32_16x16x32_bf16(
                                  af[mf], bfr[nf], acc[mf][nf], 0, 0, 0);
        __builtin_amdgcn_s_setprio(0);

        if (t + 2 < NT) asm volatile("s_waitcnt vmcnt(6)" ::: "memory");
        else            asm volatile("s_waitcnt vmcnt(0)" ::: "memory");
        rs = (rs == 2) ? 0 : rs + 1;
    }

    #pragma unroll
    for (int mf = 0; mf < 8; mf++)
        #pragma unroll
        for (int nf = 0; nf < 4; nf++)
            #pragma unroll
            for (int r = 0; r < 4; r++) {
                int row = row0 + mf * 16 + lg * 4 + r;
                int col = col0 + w * 64 + nf * 16 + l15;
                outF[(size_t)row * N + col] = acc[mf][nf][r];
            }
}

// ---------- MFMA flash attention, wave-independent (NO barriers) ----------
__global__ __launch_bounds__(256) void attn_fwd(
    const unsigned short* __restrict__ qcat,
    const unsigned short* __restrict__ kp,   // [bg][key][64]
    const unsigned short* __restrict__ vt,   // [bg][d][KTOT]
    const float* __restrict__ ls,
    unsigned short* __restrict__ attn_out)
{
    __shared__ unsigned short Pl[4][32][72];   // per-wave P tile (bf16)

    const int tid = threadIdx.x;
    const int lane = tid & 63, w = tid >> 6;
    const int l15 = lane & 15, lg = lane >> 4;

    const int wid = blockIdx.x * 4 + w;        // 0..4095
    const int hb = wid & 31;
    const int iu = wid >> 5;                   // schedule slot 0..127
    int i;
    if (iu < 32)       i = 127 - iu;
    else if (iu == 32) i = 0;
    else if (iu == 33) i = 1;
    else               i = iu - 32;
    const int h = hb & 15, b = hb >> 4, g = h >> 2;
    const int q0 = i * 32;

    int ktmax;
    if (q0 < 64) ktmax = NTILES;               // uniform rows: all keys
    else {
        int lastkey = q0 + 31 - 3024;          // max valid local key index
        ktmax = (lastkey < NBLK) ? 1 : (lastkey / 64 + 1);
    }

    const float sc = __expf(ls[h]) * 0.17677669529663687f;   // exp(ls)/sqrt(32)

    bf16x8 aq[2][2];
    const unsigned short* qbase = qcat + (((size_t)(b * 16 + h)) * T_ + q0) * 64;
    #pragma unroll
    for (int rf = 0; rf < 2; rf++)
        #pragma unroll
        for (int kh = 0; kh < 2; kh++)
            aq[rf][kh] = __builtin_bit_cast(bf16x8,
                *(const uint4*)(qbase + (size_t)(rf*16 + l15)*64 + kh*32 + lg*8));

    float m[2][4], lrun[2][4];
    #pragma unroll
    for (int rf = 0; rf < 2; rf++)
        #pragma unroll
        for (int r = 0; r < 4; r++) { m[rf][r] = -1e9f; lrun[rf][r] = 0.f; }
    f32x4 oacc[2][4] = {};

    const unsigned short* kbase = kp + ((size_t)(b * 4 + g)) * KTOT * 64;
    const unsigned short* vbase = vt + ((size_t)(b * 4 + g)) * 64 * KTOT;

    for (int kt = 0; kt < ktmax; kt++) {
        const int kb = kt * 64;

        bf16x8 bk[4][2];
        #pragma unroll
        for (int nf = 0; nf < 4; nf++) {
            int krow = kb + nf*16 + l15;
            int krc = krow < KTOT ? krow : KTOT - 1;     // clamp (masked later)
            #pragma unroll
            for (int kh = 0; kh < 2; kh++)
                bk[nf][kh] = __builtin_bit_cast(bf16x8,
                    *(const uint4*)(kbase + (size_t)krc * 64 + kh*32 + lg*8));
        }

        f32x4 s[2][4] = {};
        #pragma unroll
        for (int rf = 0; rf < 2; rf++)
            #pragma unroll
            for (int nf = 0; nf < 4; nf++)
                #pragma unroll
                for (int kh = 0; kh < 2; kh++)
                    s[rf][nf] = __builtin_amdgcn_mfma_f32_16x16x32_bf16(
                                    aq[rf][kh], bk[nf][kh], s[rf][nf], 0, 0, 0);

        bf16x8 bv[4][2];
        #pragma unroll
        for (int nfv = 0; nfv < 4; nfv++)
            #pragma unroll
            for (int kh = 0; kh < 2; kh++) {
                int kc = kb + kh*32 + lg*8;
                int kcc = (kc + 8 <= KTOT) ? kc : KTOT - 8;  // clamp (P=0 there)
                bv[nfv][kh] = __builtin_bit_cast(bf16x8,
                    *(const uint4*)(vbase + (size_t)(nfv*16 + l15) * KTOT + kcc));
            }

        #pragma unroll
        for (int rf = 0; rf < 2; rf++) {
            #pragma unroll
            for (int r = 0; r < 4; r++) {
                const int qpos = q0 + rf*16 + lg*4 + r;
                float vals[4];
                float tmax = -INFINITY;
                #pragma unroll
                for (int nf = 0; nf < 4; nf++) {
                    int key = kb + nf*16 + l15;
                    float v = s[rf][nf][r] * sc;
                    int kpos = (key < NBLK) ? key * 64 + 63 : 3024 + key;
                    v = (key < KTOT) ? ((kpos <= qpos) ? v : -1e9f) : -INFINITY;
                    vals[nf] = v;
                    tmax = fmaxf(tmax, v);
                }
                #pragma unroll
                for (int d = 1; d < 16; d <<= 1)
                    tmax = fmaxf(tmax, __shfl_xor(tmax, d));
                float mn = fmaxf(m[rf][r], tmax);
                float scl = __expf(m[rf][r] - mn);
                m[rf][r] = mn;
                float rs = 0.f;
                #pragma unroll
                for (int nf = 0; nf < 4; nf++) {
                    unsigned short pb = f2bf(__expf(vals[nf] - mn));
                    rs += bf2f(pb);          // sum the ROUNDED p: exact convex comb
                    Pl[w][rf*16 + lg*4 + r][nf*16 + l15] = pb;
                }
                #pragma unroll
                for (int d = 1; d < 16; d <<= 1)
                    rs += __shfl_xor(rs, d);
                lrun[rf][r] = lrun[rf][r] * scl + rs;
                #pragma unroll
                for (int nfv = 0; nfv < 4; nfv++)
                    oacc[rf][nfv][r] *= scl;
            }
        }

        #pragma unroll
        for (int rf = 0; rf < 2; rf++) {
            bf16x8 pa[2];
            #pragma unroll
            for (int kh = 0; kh < 2; kh++)
                pa[kh] = __builtin_bit_cast(bf16x8,
                    *(const uint4*)&Pl[w][rf*16 + l15][kh*32 + lg*8]);
            #pragma unroll
            for (int nfv = 0; nfv < 4; nfv++)
                #pragma unroll
                for (int kh = 0; kh < 2; kh++)
                    oacc[rf][nfv] = __builtin_amdgcn_mfma_f32_16x16x32_bf16(
                                        pa[kh], bv[nfv][kh], oacc[rf][nfv], 0, 0, 0);
        }
    }

    #pragma unroll
    for (int rf = 0; rf < 2; rf++) {
        #pragma unroll
        for (int r = 0; r < 4; r++) {
            float inv = 1.f / lrun[rf][r];
            int q = q0 + rf*16 + lg*4 + r;
            size_t obase = ((size_t)(b * T_ + q)) * 1024 + h * 64;
            #pragma unroll
            for (int nfv = 0; nfv < 4; nfv++)
                attn_out[obase + nfv*16 + l15] = f2bf(oacc[rf][nfv][r] * inv);
        }
    }
}

// ---------- host launch ----------
extern "C" void kernel_launch(void* const* d_in, const int* in_sizes, int n_in,
                              void* d_out, int out_size, void* d_ws, size_t ws_size,
                              hipStream_t stream) {
    const float* x      = (const float*)d_in[0];
    const float* Wq_sem = (const float*)d_in[1];
    const float* Wk_sem = (const float*)d_in[2];
    const float* Wq_geo = (const float*)d_in[3];
    const float* Wk_geo = (const float*)d_in[4];
    const float* Wv     = (const float*)d_in[5];
    const float* Wo     = (const float*)d_in[6];
    const float* ls     = (const float*)d_in[7];

    char* w = (char*)d_ws;
    auto alloc = [&](size_t bytes) {
        char* p = w;
        w += (bytes + 255) & ~(size_t)255;
        return p;
    };
    unsigned short* xb    = (unsigned short*)alloc((size_t)8192 * 2048 * 2);
    unsigned short* WcatT = (unsigned short*)alloc((size_t)1536 * 2048 * 2);
    unsigned short* WoT   = (unsigned short*)alloc((size_t)2048 * 1024 * 2);
    unsigned short* qcat  = (unsigned short*)alloc((size_t)2 * 16 * 4096 * 64 * 2);
    unsigned short* kp    = (unsigned short*)alloc((size_t)2 * 4 * 1072 * 64 * 2);
    unsigned short* vt    = (unsigned short*)alloc((size_t)2 * 4 * 1072 * 64 * 2);
    unsigned short* aout  = (unsigned short*)alloc((size_t)8192 * 1024 * 2);

    hipFuncSetAttribute(reinterpret_cast<const void*>(&gemmProj),
                        hipFuncAttributeMaxDynamicSharedMemorySize, 49152);
    hipFuncSetAttribute(reinterpret_cast<const void*>(&gemmWo),
                        hipFuncAttributeMaxDynamicSharedMemorySize, 73728);

    // 1) weights transpose + x->bf16 in one launch (co-scheduled)
    prep_all<<<6144, 256, 0, stream>>>(
        x, Wq_sem, Wq_geo, Wk_sem, Wk_geo, Wv, Wo, xb, WcatT, WoT);

    // 2) fused projection GEMM (+RoPE +pooling) -> qcat / kp / vt
    gemmProj<<<768, 256, 49152, stream>>>(
        xb, WcatT, qcat, kp, vt, 2048, 12);

    // 3) wave-independent MFMA flash attention
    attn_fwd<<<dim3(1024), 256, 0, stream>>>(qcat, kp, vt, ls, aout);

    // 4) output projection -> d_out (fp32); 128x256 tile, 512 blocks @ 2/CU
    gemmWo<<<512, 256, 73728, stream>>>(
        aout, WoT, (float*)d_out, 2048, 1024, 8);
}

// Round 16
// 179.809 us; speedup vs baseline: 1.0438x; 1.0438x over previous
//
#include <hip/hip_runtime.h>
#include <math.h>

// ---------- constants ----------
#define B_  2
#define T_  4096
#define DM  2048
#define H_  16
#define HKV 4
#define DV_ 64
#define MB_ 64
#define LW_ 1024
#define REMOTE 3072     // T - LW
#define NBLK 48         // REMOTE/MB
#define KTOT 1072       // NBLK + LW
#define NTILES 17       // ceil(1072/64)

typedef __bf16 bf16x8 __attribute__((ext_vector_type(8)));
typedef float  f32x4  __attribute__((ext_vector_type(4)));

__device__ __forceinline__ float bf2f(unsigned short u) {
    unsigned int x = ((unsigned int)u) << 16;
    return __builtin_bit_cast(float, x);
}
__device__ __forceinline__ unsigned short f2bf(float f) {
    unsigned int x = __builtin_bit_cast(unsigned int, f);
    x = x + 0x7fffu + ((x >> 16) & 1u);   // round-to-nearest-even
    return (unsigned short)(x >> 16);
}

// async global->LDS, 16B per lane; LDS dest = wave-uniform base + lane*16
__device__ __forceinline__ void gload16(const void* gsrc, unsigned short* ldst) {
    __builtin_amdgcn_global_load_lds(
        (const __attribute__((address_space(1))) void*)gsrc,
        (__attribute__((address_space(3))) void*)ldst,
        16, 0, 0);
}

// ---------- ALL weight transposes in one launch ----------
__global__ void transpose_all(const float* __restrict__ Wq_sem,
                              const float* __restrict__ Wq_geo,
                              const float* __restrict__ Wk_sem,
                              const float* __restrict__ Wk_geo,
                              const float* __restrict__ Wv,
                              const float* __restrict__ Wo,
                              unsigned short* __restrict__ WcatT,
                              unsigned short* __restrict__ WoT) {
    __shared__ float tile[32][33];
    const int bid = blockIdx.x;
    const float* src; unsigned short* dst; int R, C, tiles_x, lt;
    if (bid < 1024)      { src = Wq_sem; dst = WcatT;                       R = 2048; C = 512;  tiles_x = 16; lt = bid; }
    else if (bid < 2048) { src = Wq_geo; dst = WcatT + (size_t)512  * 2048; R = 2048; C = 512;  tiles_x = 16; lt = bid - 1024; }
    else if (bid < 2304) { src = Wk_sem; dst = WcatT + (size_t)1024 * 2048; R = 2048; C = 128;  tiles_x = 4;  lt = bid - 2048; }
    else if (bid < 2560) { src = Wk_geo; dst = WcatT + (size_t)1152 * 2048; R = 2048; C = 128;  tiles_x = 4;  lt = bid - 2304; }
    else if (bid < 3072) { src = Wv;     dst = WcatT + (size_t)1280 * 2048; R = 2048; C = 256;  tiles_x = 8;  lt = bid - 2560; }
    else                 { src = Wo;     dst = WoT;                         R = 1024; C = 2048; tiles_x = 64; lt = bid - 3072; }
    const int ct = lt % tiles_x, rt = lt / tiles_x;
    const int tx = threadIdx.x, ty = threadIdx.y;
    #pragma unroll
    for (int i = ty; i < 32; i += 8)
        tile[i][tx] = src[(size_t)(rt * 32 + i) * C + ct * 32 + tx];
    __syncthreads();
    #pragma unroll
    for (int i = ty; i < 32; i += 8)
        dst[(size_t)(ct * 32 + i) * R + rt * 32 + tx] = f2bf(tile[tx][i]);
}

// ---------- projection GEMM: 128x128, ring-3, fused cvt+RoPE+pool ----------
// R13 choreography (measured 104 us, conflicts 0): A = x in FP32 via T14
// reg-stage — issue f32 loads for t+2 at top, cvt + swizzled ds_write of
// tile t+1 AFTER the MFMA phase; B via gload_lds.  vmcnt(6)+lgkmcnt(0)+
// barrier per tile.
__global__ __launch_bounds__(256, 3) void gemmProj(
    const float* __restrict__ Axf0,
    const unsigned short* __restrict__ BT,
    unsigned short* __restrict__ qcat,
    unsigned short* __restrict__ kp,    // [bg][key][64]
    unsigned short* __restrict__ vt,    // [bg][d][KTOT]
    int K, int nbx)
{
    extern __shared__ __align__(16) unsigned short lds[];  // 3*8192 ushorts

    const int tid = threadIdx.x;
    const int lane = tid & 63, w = tid >> 6;   // 4 waves: 2x2
    const int wr = w >> 1, wc = w & 1;
    const int l15 = lane & 15, lg = lane >> 4;

    const int cpx = gridDim.x >> 3;
    const int swz = (blockIdx.x & 7) * cpx + (blockIdx.x >> 3);
    const int bx = swz % nbx, by = swz / nbx;
    const int row0 = by * 128, col0 = bx * 128;

    const int scol = ((lane & 3) ^ ((lane >> 3) & 3)) * 8;
    const int srA = w * 16 + (lane >> 2);
    const unsigned short* Bg = BT + (size_t)col0 * K;

    const int ar0 = tid >> 2, ar1 = ar0 + 64, ac = tid & 3;
    const int agc0 = (ac ^ ((ar0 >> 1) & 3)) * 8;
    const int agc1 = (ac ^ ((ar1 >> 1) & 3)) * 8;
    const float* Axf = Axf0 + (size_t)row0 * K;

    const int rdsw = (lg ^ ((l15 >> 1) & 3)) * 8;
    const int aoff = (wr * 64 + l15) * 32 + rdsw;
    const int boff = (wc * 64 + l15) * 32 + rdsw;

    const int NT = K >> 5;
    f32x4 acc[4][4] = {};

    auto stageB = [&](int s, int kk) {
        unsigned short* sb = lds + s * 8192 + 4096;
        #pragma unroll
        for (int j = 0; j < 2; j++)
            gload16(Bg + (size_t)(srA + j * 64) * K + kk + scol,
                    sb + (j * 256 + w * 64) * 8);
    };
    auto issueA = [&](float4* ra, int kk) {
        ra[0] = *(const float4*)&Axf[(size_t)ar0 * K + kk + agc0];
        ra[1] = *(const float4*)&Axf[(size_t)ar0 * K + kk + agc0 + 4];
        ra[2] = *(const float4*)&Axf[(size_t)ar1 * K + kk + agc1];
        ra[3] = *(const float4*)&Axf[(size_t)ar1 * K + kk + agc1 + 4];
    };
    auto writeA = [&](int s, const float4* ra) {
        unsigned short* sa = lds + s * 8192;
        bf16x8 v0, v1;
        v0[0] = (__bf16)ra[0].x; v0[1] = (__bf16)ra[0].y;
        v0[2] = (__bf16)ra[0].z; v0[3] = (__bf16)ra[0].w;
        v0[4] = (__bf16)ra[1].x; v0[5] = (__bf16)ra[1].y;
        v0[6] = (__bf16)ra[1].z; v0[7] = (__bf16)ra[1].w;
        v1[0] = (__bf16)ra[2].x; v1[1] = (__bf16)ra[2].y;
        v1[2] = (__bf16)ra[2].z; v1[3] = (__bf16)ra[2].w;
        v1[4] = (__bf16)ra[3].x; v1[5] = (__bf16)ra[3].y;
        v1[6] = (__bf16)ra[3].z; v1[7] = (__bf16)ra[3].w;
        *(uint4*)&sa[ar0 * 32 + ac * 8] = __builtin_bit_cast(uint4, v0);
        *(uint4*)&sa[ar1 * 32 + ac * 8] = __builtin_bit_cast(uint4, v1);
    };
    auto mfmaTile = [&](int rs_) {
        const unsigned short* As_ = lds + rs_ * 8192;
        const unsigned short* Bs_ = As_ + 4096;
        bf16x8 af[4], bfr[4];
        #pragma unroll
        for (int mf = 0; mf < 4; mf++)
            af[mf] = __builtin_bit_cast(bf16x8, *(const uint4*)&As_[aoff + mf * 512]);
        #pragma unroll
        for (int nf = 0; nf < 4; nf++)
            bfr[nf] = __builtin_bit_cast(bf16x8, *(const uint4*)&Bs_[boff + nf * 512]);
        __builtin_amdgcn_s_setprio(1);
        #pragma unroll
        for (int mf = 0; mf < 4; mf++)
            #pragma unroll
            for (int nf = 0; nf < 4; nf++)
                acc[mf][nf] = __builtin_amdgcn_mfma_f32_16x16x32_bf16(
                    af[mf], bfr[nf], acc[mf][nf], 0, 0, 0);
        __builtin_amdgcn_s_setprio(0);
    };

    // prologue: B(0),B(1) async; A(0),A(1) -> regs; write A(0)
    stageB(0, 0);
    stageB(1, 32);
    __builtin_amdgcn_sched_barrier(0);
    float4 rA[4], rB[4];
    issueA(rA, 0);
    issueA(rB, 32);
    writeA(0, rA);                 // waits A(0) => B(0),B(1) retired (FIFO)
    asm volatile("s_waitcnt lgkmcnt(0)" ::: "memory");
    __builtin_amdgcn_s_barrier();

    int rs = 0;
    for (int t = 0; t < NT; t += 2) {
        // ---- even: read tile t; issue t+2; write A(t+1) from rB ----
        {
            if (t + 2 < NT) {
                stageB(rs == 0 ? 2 : rs - 1, (t + 2) << 5);
                __builtin_amdgcn_sched_barrier(0);   // B before A in FIFO
                issueA(rA, (t + 2) << 5);
            }
            mfmaTile(rs);
            int s1 = (rs == 2) ? 0 : rs + 1;
            writeA(s1, rB);                 // waits A(t+1) => B(t+1) retired
            asm volatile("s_waitcnt vmcnt(6)" ::: "memory");
            asm volatile("s_waitcnt lgkmcnt(0)" ::: "memory");
            __builtin_amdgcn_s_barrier();
            rs = s1;
        }
        // ---- odd: read tile t+1; issue t+3; write A(t+2) from rA ----
        {
            if (t + 3 < NT) {
                stageB(rs == 0 ? 2 : rs - 1, (t + 3) << 5);
                __builtin_amdgcn_sched_barrier(0);
                issueA(rB, (t + 3) << 5);
            }
            mfmaTile(rs);
            int s1 = (rs == 2) ? 0 : rs + 1;
            if (t + 2 < NT) writeA(s1, rA);
            asm volatile("s_waitcnt vmcnt(6)" ::: "memory");
            asm volatile("s_waitcnt lgkmcnt(0)" ::: "memory");
            __builtin_amdgcn_s_barrier();
            rs = s1;
        }
    }

    // ---- fused epilogue (validated since R8) ----
    const int cspan = col0 + wc * 64;
    const int tbase = row0 & 4095;
    const int bq = row0 >> 12;

    if ((cspan >= 512 && cspan < 1024) || (cspan >= 1152 && cspan < 1280)) {
        const float invf = exp2f(-(float)l15 * 0.8304820237218406f);
        #pragma unroll
        for (int mf = 0; mf < 4; mf++) {
            #pragma unroll
            for (int r = 0; r < 4; r++) {
                float s, c;
                sincosf((float)(tbase + wr*64 + mf*16 + lg*4 + r) * invf, &s, &c);
                float a0 = acc[mf][0][r], a1 = acc[mf][1][r];
                acc[mf][0][r] = a0 * c - a1 * s;
                acc[mf][1][r] = a1 * c + a0 * s;
                float a2 = acc[mf][2][r], a3 = acc[mf][3][r];
                acc[mf][2][r] = a2 * c - a3 * s;
                acc[mf][3][r] = a3 * c + a2 * s;
            }
        }
    }

    if (cspan < 1024) {
        #pragma unroll
        for (int nf = 0; nf < 4; nf++) {
            int col = cspan + nf * 16 + l15;
            int h = (col < 512) ? (col >> 5) : ((col - 512) >> 5);
            int d = (col < 512) ? (col & 31) : (32 + (col & 31));
            unsigned short* qb =
                qcat + (((size_t)(bq * 16 + h)) * 4096 + tbase) * 64 + d;
            #pragma unroll
            for (int mf = 0; mf < 4; mf++)
                #pragma unroll
                for (int r = 0; r < 4; r++)
                    qb[(size_t)(wr*64 + mf*16 + lg*4 + r) * 64] =
                        f2bf(acc[mf][nf][r]);
        }
    } else if (tbase >= REMOTE) {
        #pragma unroll
        for (int nf = 0; nf < 4; nf++) {
            int col = cspan + nf * 16 + l15;
            #pragma unroll
            for (int mf = 0; mf < 4; mf++)
                #pragma unroll
                for (int r = 0; r < 4; r++) {
                    int key = tbase + wr*64 + mf*16 + lg*4 + r - 3024;
                    unsigned short hv = f2bf(acc[mf][nf][r]);
                    if (col < 1280) {
                        int g, dk;
                        if (col < 1152) { g = (col - 1024) >> 5; dk = col & 31; }
                        else            { g = (col - 1152) >> 5; dk = 32 + (col & 31); }
                        kp[(((size_t)(bq*4 + g)) * KTOT + key) * 64 + dk] = hv;
                    } else {
                        int g = (col - 1280) >> 6, dv = col & 63;
                        vt[(((size_t)(bq*4 + g)) * 64 + dv) * KTOT + key] = hv;
                    }
                }
        }
    } else {
        #pragma unroll
        for (int nf = 0; nf < 4; nf++) {
            float ps = 0.f;
            #pragma unroll
            for (int mf = 0; mf < 4; mf++)
                #pragma unroll
                for (int r = 0; r < 4; r++) ps += acc[mf][nf][r];
            ps += __shfl_xor(ps, 16);
            ps += __shfl_xor(ps, 32);
            if (lane < 16) {
                int col = cspan + nf * 16 + l15;
                int key = (tbase >> 6) + wr;
                unsigned short hv = f2bf(ps * (1.f / 64.f));
                if (col < 1280) {
                    int g, dk;
                    if (col < 1152) { g = (col - 1024) >> 5; dk = col & 31; }
                    else            { g = (col - 1152) >> 5; dk = 32 + (col & 31); }
                    kp[(((size_t)(bq*4 + g)) * KTOT + key) * 64 + dk] = hv;
                } else {
                    int g = (col - 1280) >> 6, dv = col & 63;
                    vt[(((size_t)(bq*4 + g)) * 64 + dv) * KTOT + key] = hv;
                }
            }
        }
    }
}

// ---------- Wo GEMM: 128x256 tile, ring-3, counted vmcnt(6) ----------------
// (R14 config — measured fastest.)  512 blocks = 2/CU single round.
__global__ __launch_bounds__(256, 2) void gemmWo(
    const unsigned short* __restrict__ A,
    const unsigned short* __restrict__ BT,
    float* __restrict__ outF,
    int N, int K, int nbx)
{
    extern __shared__ __align__(16) unsigned short lds[];  // 3*12288 ushorts

    const int tid = threadIdx.x;
    const int lane = tid & 63, w = tid >> 6;
    const int l15 = lane & 15, lg = lane >> 4;

    const int cpx = gridDim.x >> 3;
    const int swz = (blockIdx.x & 7) * cpx + (blockIdx.x >> 3);
    const int bx = swz % nbx, by = swz / nbx;
    const int row0 = by * 128, col0 = bx * 256;

    const int scol = ((lane & 3) ^ ((lane >> 3) & 3)) * 8;
    const int srA = w * 16 + (lane >> 2);           // + j*64
    const unsigned short* Ag = A  + (size_t)row0 * K;
    const unsigned short* Bg = BT + (size_t)col0 * K;

    const int rdsw = (lg ^ ((l15 >> 1) & 3)) * 8;
    const int aoff = l15 * 32 + rdsw;               // + mf*512, mf 0..7
    const int boff = (w * 64 + l15) * 32 + rdsw;    // + nf*512

    const int NT = K >> 5;
    f32x4 acc[8][4] = {};

    auto stage = [&](int s, int kk) {
        unsigned short* sa = lds + s * 12288;
        unsigned short* sb = sa + 4096;
        #pragma unroll
        for (int j = 0; j < 2; j++)                 // A: 128 rows
            gload16(Ag + (size_t)(srA + j * 64) * K + kk + scol,
                    sa + (j * 256 + w * 64) * 8);
        #pragma unroll
        for (int j = 0; j < 4; j++)                 // B: 256 rows
            gload16(Bg + (size_t)(srA + j * 64) * K + kk + scol,
                    sb + (j * 256 + w * 64) * 8);
    };

    stage(0, 0);
    stage(1, 32);
    asm volatile("s_waitcnt vmcnt(6)" ::: "memory");   // tile0 landed

    int rs = 0;
    for (int t = 0; t < NT; ++t) {
        __builtin_amdgcn_s_barrier();
        if (t + 2 < NT) stage(rs == 0 ? 2 : rs - 1, (t + 2) << 5);

        const unsigned short* As_ = lds + rs * 12288;
        const unsigned short* Bs_ = As_ + 4096;
        bf16x8 af[8], bfr[4];
        #pragma unroll
        for (int mf = 0; mf < 8; mf++)
            af[mf] = __builtin_bit_cast(bf16x8, *(const uint4*)&As_[aoff + mf * 512]);
        #pragma unroll
        for (int nf = 0; nf < 4; nf++)
            bfr[nf] = __builtin_bit_cast(bf16x8, *(const uint4*)&Bs_[boff + nf * 512]);

        __builtin_amdgcn_s_setprio(1);
        #pragma unroll
        for (int mf = 0; mf < 8; mf++)
            #pragma unroll
            for (int nf = 0; nf < 4; nf++)
                acc[mf][nf] = __builtin_amdgcn_mfma_f32_16x16x32_bf16(
                                  af[mf], bfr[nf], acc[mf][nf], 0, 0, 0);
        __builtin_amdgcn_s_setprio(0);

        if (t + 2 < NT) asm volatile("s_waitcnt vmcnt(6)" ::: "memory");
        else            asm volatile("s_waitcnt vmcnt(0)" ::: "memory");
        rs = (rs == 2) ? 0 : rs + 1;
    }

    #pragma unroll
    for (int mf = 0; mf < 8; mf++)
        #pragma unroll
        for (int nf = 0; nf < 4; nf++)
            #pragma unroll
            for (int r = 0; r < 4; r++) {
                int row = row0 + mf * 16 + lg * 4 + r;
                int col = col0 + w * 64 + nf * 16 + l15;
                outF[(size_t)row * N + col] = acc[mf][nf][r];
            }
}

// ---------- MFMA flash attention, wave-independent (NO barriers) ----------
__global__ __launch_bounds__(256) void attn_fwd(
    const unsigned short* __restrict__ qcat,
    const unsigned short* __restrict__ kp,   // [bg][key][64]
    const unsigned short* __restrict__ vt,   // [bg][d][KTOT]
    const float* __restrict__ ls,
    unsigned short* __restrict__ attn_out)
{
    __shared__ unsigned short Pl[4][32][72];   // per-wave P tile (bf16)

    const int tid = threadIdx.x;
    const int lane = tid & 63, w = tid >> 6;
    const int l15 = lane & 15, lg = lane >> 4;

    const int wid = blockIdx.x * 4 + w;        // 0..4095
    const int hb = wid & 31;
    const int iu = wid >> 5;                   // schedule slot 0..127
    int i;
    if (iu < 32)       i = 127 - iu;
    else if (iu == 32) i = 0;
    else if (iu == 33) i = 1;
    else               i = iu - 32;
    const int h = hb & 15, b = hb >> 4, g = h >> 2;
    const int q0 = i * 32;

    int ktmax;
    if (q0 < 64) ktmax = NTILES;               // uniform rows: all keys
    else {
        int lastkey = q0 + 31 - 3024;          // max valid local key index
        ktmax = (lastkey < NBLK) ? 1 : (lastkey / 64 + 1);
    }

    const float sc = __expf(ls[h]) * 0.17677669529663687f;   // exp(ls)/sqrt(32)

    bf16x8 aq[2][2];
    const unsigned short* qbase = qcat + (((size_t)(b * 16 + h)) * T_ + q0) * 64;
    #pragma unroll
    for (int rf = 0; rf < 2; rf++)
        #pragma unroll
        for (int kh = 0; kh < 2; kh++)
            aq[rf][kh] = __builtin_bit_cast(bf16x8,
                *(const uint4*)(qbase + (size_t)(rf*16 + l15)*64 + kh*32 + lg*8));

    float m[2][4], lrun[2][4];
    #pragma unroll
    for (int rf = 0; rf < 2; rf++)
        #pragma unroll
        for (int r = 0; r < 4; r++) { m[rf][r] = -1e9f; lrun[rf][r] = 0.f; }
    f32x4 oacc[2][4] = {};

    const unsigned short* kbase = kp + ((size_t)(b * 4 + g)) * KTOT * 64;
    const unsigned short* vbase = vt + ((size_t)(b * 4 + g)) * 64 * KTOT;

    for (int kt = 0; kt < ktmax; kt++) {
        const int kb = kt * 64;

        bf16x8 bk[4][2];
        #pragma unroll
        for (int nf = 0; nf < 4; nf++) {
            int krow = kb + nf*16 + l15;
            int krc = krow < KTOT ? krow : KTOT - 1;     // clamp (masked later)
            #pragma unroll
            for (int kh = 0; kh < 2; kh++)
                bk[nf][kh] = __builtin_bit_cast(bf16x8,
                    *(const uint4*)(kbase + (size_t)krc * 64 + kh*32 + lg*8));
        }

        f32x4 s[2][4] = {};
        #pragma unroll
        for (int rf = 0; rf < 2; rf++)
            #pragma unroll
            for (int nf = 0; nf < 4; nf++)
                #pragma unroll
                for (int kh = 0; kh < 2; kh++)
                    s[rf][nf] = __builtin_amdgcn_mfma_f32_16x16x32_bf16(
                                    aq[rf][kh], bk[nf][kh], s[rf][nf], 0, 0, 0);

        bf16x8 bv[4][2];
        #pragma unroll
        for (int nfv = 0; nfv < 4; nfv++)
            #pragma unroll
            for (int kh = 0; kh < 2; kh++) {
                int kc = kb + kh*32 + lg*8;
                int kcc = (kc + 8 <= KTOT) ? kc : KTOT - 8;  // clamp (P=0 there)
                bv[nfv][kh] = __builtin_bit_cast(bf16x8,
                    *(const uint4*)(vbase + (size_t)(nfv*16 + l15) * KTOT + kcc));
            }

        #pragma unroll
        for (int rf = 0; rf < 2; rf++) {
            #pragma unroll
            for (int r = 0; r < 4; r++) {
                const int qpos = q0 + rf*16 + lg*4 + r;
                float vals[4];
                float tmax = -INFINITY;
                #pragma unroll
                for (int nf = 0; nf < 4; nf++) {
                    int key = kb + nf*16 + l15;
                    float v = s[rf][nf][r] * sc;
                    int kpos = (key < NBLK) ? key * 64 + 63 : 3024 + key;
                    v = (key < KTOT) ? ((kpos <= qpos) ? v : -1e9f) : -INFINITY;
                    vals[nf] = v;
                    tmax = fmaxf(tmax, v);
                }
                #pragma unroll
                for (int d = 1; d < 16; d <<= 1)
                    tmax = fmaxf(tmax, __shfl_xor(tmax, d));
                float mn = fmaxf(m[rf][r], tmax);
                float scl = __expf(m[rf][r] - mn);
                m[rf][r] = mn;
                float rs = 0.f;
                #pragma unroll
                for (int nf = 0; nf < 4; nf++) {
                    unsigned short pb = f2bf(__expf(vals[nf] - mn));
                    rs += bf2f(pb);          // sum the ROUNDED p: exact convex comb
                    Pl[w][rf*16 + lg*4 + r][nf*16 + l15] = pb;
                }
                #pragma unroll
                for (int d = 1; d < 16; d <<= 1)
                    rs += __shfl_xor(rs, d);
                lrun[rf][r] = lrun[rf][r] * scl + rs;
                #pragma unroll
                for (int nfv = 0; nfv < 4; nfv++)
                    oacc[rf][nfv][r] *= scl;
            }
        }

        #pragma unroll
        for (int rf = 0; rf < 2; rf++) {
            bf16x8 pa[2];
            #pragma unroll
            for (int kh = 0; kh < 2; kh++)
                pa[kh] = __builtin_bit_cast(bf16x8,
                    *(const uint4*)&Pl[w][rf*16 + l15][kh*32 + lg*8]);
            #pragma unroll
            for (int nfv = 0; nfv < 4; nfv++)
                #pragma unroll
                for (int kh = 0; kh < 2; kh++)
                    oacc[rf][nfv] = __builtin_amdgcn_mfma_f32_16x16x32_bf16(
                                        pa[kh], bv[nfv][kh], oacc[rf][nfv], 0, 0, 0);
        }
    }

    #pragma unroll
    for (int rf = 0; rf < 2; rf++) {
        #pragma unroll
        for (int r = 0; r < 4; r++) {
            float inv = 1.f / lrun[rf][r];
            int q = q0 + rf*16 + lg*4 + r;
            size_t obase = ((size_t)(b * T_ + q)) * 1024 + h * 64;
            #pragma unroll
            for (int nfv = 0; nfv < 4; nfv++)
                attn_out[obase + nfv*16 + l15] = f2bf(oacc[rf][nfv][r] * inv);
        }
    }
}

// ---------- host launch ----------
extern "C" void kernel_launch(void* const* d_in, const int* in_sizes, int n_in,
                              void* d_out, int out_size, void* d_ws, size_t ws_size,
                              hipStream_t stream) {
    const float* x      = (const float*)d_in[0];
    const float* Wq_sem = (const float*)d_in[1];
    const float* Wk_sem = (const float*)d_in[2];
    const float* Wq_geo = (const float*)d_in[3];
    const float* Wk_geo = (const float*)d_in[4];
    const float* Wv     = (const float*)d_in[5];
    const float* Wo     = (const float*)d_in[6];
    const float* ls     = (const float*)d_in[7];

    char* w = (char*)d_ws;
    auto alloc = [&](size_t bytes) {
        char* p = w;
        w += (bytes + 255) & ~(size_t)255;
        return p;
    };
    unsigned short* WcatT = (unsigned short*)alloc((size_t)1536 * 2048 * 2);
    unsigned short* WoT   = (unsigned short*)alloc((size_t)2048 * 1024 * 2);
    unsigned short* qcat  = (unsigned short*)alloc((size_t)2 * 16 * 4096 * 64 * 2);
    unsigned short* kp    = (unsigned short*)alloc((size_t)2 * 4 * 1072 * 64 * 2);
    unsigned short* vt    = (unsigned short*)alloc((size_t)2 * 4 * 1072 * 64 * 2);
    unsigned short* aout  = (unsigned short*)alloc((size_t)8192 * 1024 * 2);

    hipFuncSetAttribute(reinterpret_cast<const void*>(&gemmProj),
                        hipFuncAttributeMaxDynamicSharedMemorySize, 49152);
    hipFuncSetAttribute(reinterpret_cast<const void*>(&gemmWo),
                        hipFuncAttributeMaxDynamicSharedMemorySize, 73728);

    // 1) all weight transposes in ONE launch (no x cvt — fused into proj)
    transpose_all<<<5120, dim3(32, 8), 0, stream>>>(
        Wq_sem, Wq_geo, Wk_sem, Wk_geo, Wv, Wo, WcatT, WoT);

    // 2) fused projection GEMM (cvt + RoPE + pooling) -> qcat / kp / vt
    gemmProj<<<768, 256, 49152, stream>>>(
        x, WcatT, qcat, kp, vt, 2048, 12);

    // 3) wave-independent MFMA flash attention
    attn_fwd<<<dim3(1024), 256, 0, stream>>>(qcat, kp, vt, ls, aout);

    // 4) output projection -> d_out (fp32); 128x256 tile, 512 blocks @ 2/CU
    gemmWo<<<512, 256, 73728, stream>>>(
        aout, WoT, (float*)d_out, 2048, 1024, 8);
}